// Round 12
// baseline (296.561 us; speedup 1.0000x reference)
//
#include <hip/hip_runtime.h>

#define Nn 50000
#define Ee 600000
#define Rr 4
#define NBIN 200704             // 196*1024, padded for int4 scan
#define BN_EPS 1e-5f
#define ECAP 1024               // LDS edge-list cap per relation per block

typedef __bf16 bfrag  __attribute__((ext_vector_type(8)));
typedef float  f32x4  __attribute__((ext_vector_type(4)));

__device__ __forceinline__ unsigned short f2b(float f) {
    union { float f; unsigned int u; } v; v.f = f;
    return (unsigned short)((v.u + 0x7FFFu + ((v.u >> 16) & 1u)) >> 16);
}
__device__ __forceinline__ float b2f(unsigned short u) {
    union { unsigned int u; float f; } v; v.u = ((unsigned int)u) << 16; return v.f;
}

// ---- prep: xbf (blocks 0..12499) | wt (12500..13075) | hist (13076..15419) ----
__global__ __launch_bounds__(256) void prep_k(
    const float* __restrict__ x, const float* __restrict__ W1,
    const float* __restrict__ W2, const float* __restrict__ Wself,
    const int* __restrict__ ei, const int* __restrict__ et,
    unsigned int* __restrict__ xb, unsigned short* __restrict__ WT,
    int* __restrict__ hist)
{
    int b = blockIdx.x;
    if (b < 12500) {
        int i = b * 256 + threadIdx.x;
        float2 v = ((const float2*)x)[i];
        xb[i] = ((unsigned int)f2b(v.y) << 16) | f2b(v.x);
    } else if (b < 13076) {
        int idx = (b - 12500) * 256 + threadIdx.x;   // < 147456
        int mat = idx >> 14, rem = idx & 16383;
        int n = rem >> 7, k = rem & 127;
        const float* src = (mat < 4) ? (W1 + mat * 16384)
                         : (mat < 8) ? (W2 + (mat - 4) * 16384) : Wself;
        WT[idx] = f2b(src[k * 128 + n]);
    } else {
        int e = (b - 13076) * 256 + threadIdx.x;
        if (e < Ee) atomicAdd(&hist[et[e] * Nn + ei[e]], 1);
    }
}

// ---- exclusive scan over NBIN (block-local) ----
__global__ __launch_bounds__(256) void scan1_k(
    const int* __restrict__ hist, int* __restrict__ offs, int* __restrict__ bsum)
{
    int t = threadIdx.x, b = blockIdx.x;
    int base = b * 1024 + t * 4;
    int4 c = *(const int4*)(hist + base);
    int s = c.x + c.y + c.z + c.w;
    __shared__ int tmp[256];
    tmp[t] = s; __syncthreads();
    for (int off = 1; off < 256; off <<= 1) {
        int v = (t >= off) ? tmp[t - off] : 0;
        __syncthreads(); tmp[t] += v; __syncthreads();
    }
    int excl = tmp[t] - s;
    int4 o; o.x = excl; o.y = excl + c.x; o.z = o.y + c.y; o.w = o.z + c.z;
    *(int4*)(offs + base) = o;
    if (t == 255) bsum[b] = tmp[255];
}
// block b adds sum of bsum[0..b-1]
__global__ __launch_bounds__(256) void scan3_k(
    int* __restrict__ offs, int* __restrict__ cur, const int* __restrict__ bsum)
{
    int t = threadIdx.x, b = blockIdx.x;
    __shared__ int tmp[256];
    tmp[t] = (t < b) ? bsum[t] : 0;
    __syncthreads();
    for (int off = 128; off > 0; off >>= 1) {
        if (t < off) tmp[t] += tmp[t + off];
        __syncthreads();
    }
    int add = tmp[0];
    int base = b * 1024 + t * 4;
    int4 o = *(int4*)(offs + base);
    o.x += add; o.y += add; o.z += add; o.w += add;
    *(int4*)(offs + base) = o;
    *(int4*)(cur + base) = o;
}

// ---- bucket fill ----
__global__ __launch_bounds__(256) void fill_k(
    const int* __restrict__ ei, const int* __restrict__ et,
    int* __restrict__ cur, int* __restrict__ ssrc)
{
    int e = blockIdx.x * 256 + threadIdx.x;
    if (e >= Ee) return;
    int bin = et[e] * Nn + ei[e];
    int pos = atomicAdd(&cur[bin], 1);
    ssrc[pos] = ei[Ee + e];
}

#define ACC_QUADP(A_, u0_, u1_, u2_, u3_)                                 \
    do {                                                                  \
        unsigned int uu[16] = {u0_.x,u0_.y,u0_.z,u0_.w, u1_.x,u1_.y,u1_.z,u1_.w, \
                               u2_.x,u2_.y,u2_.z,u2_.w, u3_.x,u3_.y,u3_.z,u3_.w}; \
        _Pragma("unroll")                                                 \
        for (int jj = 0; jj < 16; ++jj) {                                 \
            A_[2*jj]   += b2f((unsigned short)(uu[jj] & 0xFFFF));         \
            A_[2*jj+1] += b2f((unsigned short)(uu[jj] >> 16));            \
        }                                                                 \
    } while (0)

// ---- FUSED pair: dual-relation gather (2 chains, 2x MLP) -> gemm1 r0,r1 ->
//      h1(bf16) + BN stats. 128-row tiles, 512 thr, grid (391, 2) ----
__global__ __launch_bounds__(512) void gemm1f_k(
    const unsigned int* __restrict__ xb, const int* __restrict__ offs,
    const int* __restrict__ ssrc, const unsigned short* __restrict__ WT,
    const float* __restrict__ b1, unsigned short* __restrict__ h,
    float* __restrict__ gsum, float* __restrict__ gsq)
{
    const int r0 = blockIdx.y * 2, r1 = r0 + 1;
    const int n0 = blockIdx.x * 128;
    const int t  = threadIdx.x;

    __shared__ __attribute__((aligned(16))) __bf16 As[128][136];
    __shared__ __attribute__((aligned(16))) __bf16 Ws[128][136];
    __shared__ float s_sum[256], s_sq[256];
    __shared__ int s_off0[129], s_off1[129];
    __shared__ int s_e0[ECAP], s_e1[ECAP];

    if (t < 256) { s_sum[t] = 0.f; s_sq[t] = 0.f; }
    const int rows = (Nn - n0 < 128) ? (Nn - n0) : 128;
    if (t <= rows) s_off0[t] = offs[r0 * Nn + n0 + t];
    else if (t >= 256 && t - 256 <= rows) s_off1[t - 256] = offs[r1 * Nn + n0 + (t - 256)];
    __syncthreads();

    const int eb0 = s_off0[0], ec0 = s_off0[rows] - eb0;
    const int eb1 = s_off1[0], ec1 = s_off1[rows] - eb1;
    const bool inl0 = (ec0 <= ECAP), inl1 = (ec1 <= ECAP);
    if (inl0) for (int i = t; i < ec0; i += 512) s_e0[i] = ssrc[eb0 + i];
    if (inl1) for (int i = t; i < ec1; i += 512) s_e1[i] = ssrc[eb1 + i];
    {   // stage W1_r0
        const unsigned short* Wr = WT + r0 * 16384;
        for (int i = t; i < 2048; i += 512) {
            int n = i >> 4, kc = (i & 15) << 3;
            *(uint4*)&Ws[n][kc] = *(const uint4*)(Wr + n * 128 + kc);
        }
    }
    __syncthreads();

    // dual gather: h0_r = x[dst] + sum x[src]; 4 thr/row, 16 uints each
    unsigned int pk1[16];
    {
        const int row = t >> 2, q = t & 3, gm = n0 + row;
        float a0[32], a1[32];
#pragma unroll
        for (int j = 0; j < 32; ++j) { a0[j] = 0.f; a1[j] = 0.f; }
        if (gm < Nn) {
            const uint4* xr = (const uint4*)(xb + (size_t)gm * 64 + q * 16);
            uint4 u0 = xr[0], u1 = xr[1], u2 = xr[2], u3 = xr[3];
            ACC_QUADP(a0, u0, u1, u2, u3);
#pragma unroll
            for (int j = 0; j < 32; ++j) a1[j] = a0[j];
            int j0 = s_off0[row] - eb0, je0 = s_off0[row + 1] - eb0;
            int j1 = s_off1[row] - eb1, je1 = s_off1[row + 1] - eb1;
            while (j0 < je0 || j1 < je1) {
                bool m0 = j0 < je0, m1 = j1 < je1;
                uint4 c0, c1, c2, c3, e0, e1, e2, e3;
                if (m0) {
                    int s = inl0 ? s_e0[j0] : ssrc[eb0 + j0];
                    const uint4* p = (const uint4*)(xb + (size_t)s * 64 + q * 16);
                    c0 = p[0]; c1 = p[1]; c2 = p[2]; c3 = p[3];
                }
                if (m1) {
                    int s = inl1 ? s_e1[j1] : ssrc[eb1 + j1];
                    const uint4* p = (const uint4*)(xb + (size_t)s * 64 + q * 16);
                    e0 = p[0]; e1 = p[1]; e2 = p[2]; e3 = p[3];
                }
                if (m0) { ACC_QUADP(a0, c0, c1, c2, c3); ++j0; }
                if (m1) { ACC_QUADP(a1, e0, e1, e2, e3); ++j1; }
            }
        }
        unsigned int pk0[16];
#pragma unroll
        for (int j = 0; j < 16; ++j) {
            pk0[j] = ((unsigned int)f2b(a0[2*j+1]) << 16) | f2b(a0[2*j]);
            pk1[j] = ((unsigned int)f2b(a1[2*j+1]) << 16) | f2b(a1[2*j]);
        }
        uint4* dst = (uint4*)&As[row][q * 32];
        dst[0] = make_uint4(pk0[0],  pk0[1],  pk0[2],  pk0[3]);
        dst[1] = make_uint4(pk0[4],  pk0[5],  pk0[6],  pk0[7]);
        dst[2] = make_uint4(pk0[8],  pk0[9],  pk0[10], pk0[11]);
        dst[3] = make_uint4(pk0[12], pk0[13], pk0[14], pk0[15]);
    }
    __syncthreads();

    const int w = t >> 6, l = t & 63, ln = l & 15, quad = l >> 4;
    // MFMA r0
    f32x4 acc0[8];
#pragma unroll
    for (int c = 0; c < 8; ++c) acc0[c] = (f32x4){0.f,0.f,0.f,0.f};
#pragma unroll
    for (int kk = 0; kk < 4; ++kk) {
        int ks = kk * 32 + quad * 8;
        bfrag a = *(const bfrag*)&As[w * 16 + ln][ks];
#pragma unroll
        for (int c = 0; c < 8; ++c) {
            bfrag b = *(const bfrag*)&Ws[c * 16 + ln][ks];
            acc0[c] = __builtin_amdgcn_mfma_f32_16x16x32_bf16(a, b, acc0[c], 0, 0, 0);
        }
    }
    __syncthreads();

    // swap in r1: A-tile from pk1, W1_r1
    {
        const int row = t >> 2, q = t & 3;
        uint4* dst = (uint4*)&As[row][q * 32];
        dst[0] = make_uint4(pk1[0],  pk1[1],  pk1[2],  pk1[3]);
        dst[1] = make_uint4(pk1[4],  pk1[5],  pk1[6],  pk1[7]);
        dst[2] = make_uint4(pk1[8],  pk1[9],  pk1[10], pk1[11]);
        dst[3] = make_uint4(pk1[12], pk1[13], pk1[14], pk1[15]);
        const unsigned short* Wr = WT + r1 * 16384;
        for (int i = t; i < 2048; i += 512) {
            int n = i >> 4, kc = (i & 15) << 3;
            *(uint4*)&Ws[n][kc] = *(const uint4*)(Wr + n * 128 + kc);
        }
    }
    __syncthreads();

    // MFMA r1
    f32x4 acc1[8];
#pragma unroll
    for (int c = 0; c < 8; ++c) acc1[c] = (f32x4){0.f,0.f,0.f,0.f};
#pragma unroll
    for (int kk = 0; kk < 4; ++kk) {
        int ks = kk * 32 + quad * 8;
        bfrag a = *(const bfrag*)&As[w * 16 + ln][ks];
#pragma unroll
        for (int c = 0; c < 8; ++c) {
            bfrag b = *(const bfrag*)&Ws[c * 16 + ln][ks];
            acc1[c] = __builtin_amdgcn_mfma_f32_16x16x32_bf16(a, b, acc1[c], 0, 0, 0);
        }
    }
    __syncthreads();

    // epilogues: r0 -> As region, r1 -> Ws region; BN stats for both
    __bf16 (*Hs)[136] = (__bf16(*)[136])Ws;
#pragma unroll
    for (int c = 0; c < 8; ++c) {
        int col = c * 16 + ln;
        float bias0 = b1[r0 * 128 + col];
        float bias1 = b1[r1 * 128 + col];
        float ps0 = 0.f, pq0 = 0.f, ps1 = 0.f, pq1 = 0.f;
#pragma unroll
        for (int reg = 0; reg < 4; ++reg) {
            int lrow = w * 16 + quad * 4 + reg;
            float v0 = acc0[c][reg] + bias0;
            float v1 = acc1[c][reg] + bias1;
            As[lrow][col] = (__bf16)v0;
            Hs[lrow][col] = (__bf16)v1;
            if (n0 + lrow < Nn) { ps0 += v0; pq0 += v0 * v0; ps1 += v1; pq1 += v1 * v1; }
        }
        ps0 += __shfl_xor(ps0, 16); pq0 += __shfl_xor(pq0, 16);
        ps0 += __shfl_xor(ps0, 32); pq0 += __shfl_xor(pq0, 32);
        ps1 += __shfl_xor(ps1, 16); pq1 += __shfl_xor(pq1, 16);
        ps1 += __shfl_xor(ps1, 32); pq1 += __shfl_xor(pq1, 32);
        if (quad == 0) {
            atomicAdd(&s_sum[col], ps0);       atomicAdd(&s_sq[col], pq0);
            atomicAdd(&s_sum[128 + col], ps1); atomicAdd(&s_sq[128 + col], pq1);
        }
    }
    __syncthreads();

    unsigned short* hr0 = h + (size_t)r0 * Nn * 128;
    unsigned short* hr1 = h + (size_t)r1 * Nn * 128;
    for (int i = t; i < 2048; i += 512) {
        int m = i >> 4, kc = (i & 15) << 3;
        int gm = n0 + m;
        if (gm < Nn) {
            *(uint4*)(hr0 + (size_t)gm * 128 + kc) = *(const uint4*)&As[m][kc];
            *(uint4*)(hr1 + (size_t)gm * 128 + kc) = *(const uint4*)&Hs[m][kc];
        }
    }
    if (t < 128) {
        atomicAdd(&gsum[r0 * 128 + t], s_sum[t]);
        atomicAdd(&gsq[r0 * 128 + t],  s_sq[t]);
    } else if (t < 256) {
        atomicAdd(&gsum[r1 * 128 + (t - 128)], s_sum[t]);
        atomicAdd(&gsq[r1 * 128 + (t - 128)],  s_sq[t]);
    }
}

// ---- out = x@W_self + sum_r relu(a*h1+c)@W2_r + biases; BN coefs computed in-block ----
__global__ __launch_bounds__(512) void gemm2f_k(
    const unsigned int* __restrict__ xb,
    const unsigned short* __restrict__ h,
    const unsigned short* __restrict__ WT,
    const float* __restrict__ bself, const float* __restrict__ b2,
    const float* __restrict__ gsum, const float* __restrict__ gsq,
    const float* __restrict__ gamma, const float* __restrict__ beta,
    float* __restrict__ out)
{
    const int n0 = blockIdx.x * 128;
    const int t  = threadIdx.x;
    __shared__ __attribute__((aligned(16))) __bf16 As[128][136];
    __shared__ __attribute__((aligned(16))) __bf16 Ws[128][136];
    __shared__ float s_cA[512], s_cC[512];

    {   // fused BN-coef computation (redundant per block, trivial)
        float mean = gsum[t] * (1.0f / Nn);
        float var  = gsq[t] * (1.0f / Nn) - mean * mean;
        float a    = gamma[t] * rsqrtf(fmaxf(var, 0.f) + BN_EPS);
        s_cA[t] = a;
        s_cC[t] = beta[t] - mean * a;
    }
    __syncthreads();

    const int w = t >> 6, l = t & 63, ln = l & 15, quad = l >> 4;
    f32x4 acc2[8];
#pragma unroll
    for (int c = 0; c < 8; ++c) acc2[c] = (f32x4){0.f,0.f,0.f,0.f};

    for (int rr = 0; rr < 5; ++rr) {
        const unsigned short* Wr = WT + (rr < 4 ? (4 + rr) : 8) * 16384;
        for (int i = t; i < 2048; i += 512) {
            int n = i >> 4, kc = (i & 15) << 3;
            *(uint4*)&Ws[n][kc] = *(const uint4*)(Wr + n * 128 + kc);
        }
        if (rr < 4) {
            const unsigned short* hrp = h + (size_t)rr * Nn * 128;
            const float* cA = s_cA + rr * 128;
            const float* cC = s_cC + rr * 128;
            for (int i = t; i < 2048; i += 512) {
                int m = i >> 4, kc = (i & 15) << 3;
                int gm = n0 + m;
                uint4 hv = make_uint4(0,0,0,0);
                if (gm < Nn) hv = *(const uint4*)(hrp + (size_t)gm * 128 + kc);
                unsigned int hu[4] = {hv.x, hv.y, hv.z, hv.w};
                unsigned int pk[4];
#pragma unroll
                for (int j = 0; j < 4; ++j) {
                    float v0 = fmaxf(cA[kc + 2*j]     * b2f((unsigned short)(hu[j] & 0xFFFF)) + cC[kc + 2*j],     0.f);
                    float v1 = fmaxf(cA[kc + 2*j + 1] * b2f((unsigned short)(hu[j] >> 16))    + cC[kc + 2*j + 1], 0.f);
                    pk[j] = ((unsigned int)f2b(v1) << 16) | f2b(v0);
                }
                *(uint4*)&As[m][kc] = make_uint4(pk[0], pk[1], pk[2], pk[3]);
            }
        } else {
            for (int i = t; i < 2048; i += 512) {
                int m = i >> 4, kc = (i & 15) << 3;
                int gm = n0 + m;
                uint4 v = make_uint4(0, 0, 0, 0);
                if (gm < Nn) v = *(const uint4*)(xb + (size_t)gm * 64 + (kc >> 1));
                *(uint4*)&As[m][kc] = v;
            }
        }
        __syncthreads();
#pragma unroll
        for (int kk = 0; kk < 4; ++kk) {
            int ks = kk * 32 + quad * 8;
            bfrag a = *(const bfrag*)&As[w * 16 + ln][ks];
#pragma unroll
            for (int c = 0; c < 8; ++c) {
                bfrag b = *(const bfrag*)&Ws[c * 16 + ln][ks];
                acc2[c] = __builtin_amdgcn_mfma_f32_16x16x32_bf16(a, b, acc2[c], 0, 0, 0);
            }
        }
        __syncthreads();
    }

    // Epilogue: fp32 transpose through Ws, coalesced stores; 2 passes of 64 rows
    float bias[8];
#pragma unroll
    for (int c = 0; c < 8; ++c) {
        int col = c * 16 + ln;
        bias[c] = bself[col] + b2[col] + b2[128 + col] + b2[256 + col] + b2[384 + col];
    }
    float* fws = (float*)Ws;
    for (int p = 0; p < 2; ++p) {
        if ((w >> 2) == p) {
#pragma unroll
            for (int c = 0; c < 8; ++c) {
                int lrow = (w & 3) * 16 + quad * 4;
                int col  = c * 16 + ln;
#pragma unroll
                for (int reg = 0; reg < 4; ++reg)
                    fws[(lrow + reg) * 132 + col] = acc2[c][reg] + bias[c];
            }
        }
        __syncthreads();
        for (int i = t; i < 2048; i += 512) {
            int m = i >> 5, kc = (i & 31) << 2;
            int gm = n0 + p * 64 + m;
            if (gm < Nn)
                *(float4*)(out + (size_t)gm * 128 + kc) = *(const float4*)&fws[m * 132 + kc];
        }
        __syncthreads();
    }
}

extern "C" void kernel_launch(void* const* d_in, const int* in_sizes, int n_in,
                              void* d_out, int out_size, void* d_ws, size_t ws_size,
                              hipStream_t stream) {
    const float* x     = (const float*)d_in[0];
    const int*   ei    = (const int*)d_in[1];
    const int*   et    = (const int*)d_in[2];
    const float* Wself = (const float*)d_in[3];
    const float* bself = (const float*)d_in[4];
    const float* W1    = (const float*)d_in[5];
    const float* b1    = (const float*)d_in[6];
    const float* gamma = (const float*)d_in[7];
    const float* beta  = (const float*)d_in[8];
    const float* W2    = (const float*)d_in[9];
    const float* b2    = (const float*)d_in[10];
    float* out = (float*)d_out;

    char* ws = (char*)d_ws;
    int*   hist  = (int*)(ws + 0);                      // 802,816
    float* gsum  = (float*)(ws + 802816);               // 2048
    float* gsq   = (float*)(ws + 804864);               // 2048
    int*   bsum  = (int*)(ws + 811008);                 // 1024
    int*   offs  = (int*)(ws + 813056);                 // 802,816
    int*   cur   = (int*)(ws + 1615872);                // 802,816
    int*   ssrc  = (int*)(ws + 2418688);                // 2,400,000
    unsigned short* h  = (unsigned short*)(ws + 4818688);   // 51,200,000
    unsigned int*   xb = (unsigned int*)(ws + 56018688);    // 12,800,000
    unsigned short* WT = (unsigned short*)(ws + 68818688);  // 294,912

    (void)hipMemsetAsync(ws, 0, 806912, stream);   // hist + gsum + gsq

    const int EB = (Ee + 255) / 256;                    // 2344
    prep_k <<<12500 + 576 + EB, 256, 0, stream>>>(x, W1, W2, Wself, ei, et, xb, WT, hist);
    scan1_k<<<196, 256, 0, stream>>>(hist, offs, bsum);
    scan3_k<<<196, 256, 0, stream>>>(offs, cur, bsum);
    fill_k <<<EB, 256, 0, stream>>>(ei, et, cur, ssrc);

    dim3 g1((Nn + 127) / 128, 2);       // (391, 2) relation pairs
    gemm1f_k<<<g1, 512, 0, stream>>>(xb, offs, ssrc, WT, b1, h, gsum, gsq);
    gemm2f_k<<<(Nn + 127) / 128, 512, 0, stream>>>(
        xb, h, WT, bself, b2, gsum, gsq, gamma, beta, out);
}